// Round 1
// baseline (8796.987 us; speedup 1.0000x reference)
//
#include <hip/hip_runtime.h>

#define NN 100000
#define NE 1600000
#define FD 128
#define OS 512   // output row stride: [feat | h1 | h2 | h3]

// ---------------- init: write feat into cols 0:128, zero cols 128:512 ----------------
__global__ void k_init_out(const float* __restrict__ feat, float* __restrict__ out) {
    const size_t total = (size_t)NN * (OS / 4);
    for (size_t i = (size_t)blockIdx.x * blockDim.x + threadIdx.x; i < total;
         i += (size_t)gridDim.x * blockDim.x) {
        size_t n = i >> 7;        // / (OS/4)
        int c4 = (int)(i & 127);  // float4 col
        float4 v = make_float4(0.f, 0.f, 0.f, 0.f);
        if (c4 < FD / 4) v = ((const float4*)feat)[n * (FD / 4) + c4];
        ((float4*)out)[i] = v;
    }
}

// ---------------- degree histogram ----------------
__global__ void k_degrees(const int* __restrict__ src, const int* __restrict__ dst,
                          float* __restrict__ deg_out, float* __restrict__ deg_in) {
    for (int e = blockIdx.x * blockDim.x + threadIdx.x; e < NE;
         e += gridDim.x * blockDim.x) {
        unsafeAtomicAdd(&deg_out[src[e]], 1.0f);
        unsafeAtomicAdd(&deg_in[dst[e]], 1.0f);
    }
}

__global__ void k_invsqrt(const float* __restrict__ deg, float* __restrict__ inv, int n) {
    int i = blockIdx.x * blockDim.x + threadIdx.x;
    if (i < n) inv[i] = rsqrtf(fmaxf(deg[i], 1.0f));
}

// ---------------- GEMM: tmp[r][:] = inv_out[r] * (h[r][:] @ W) ----------------
// block = 256 threads, 128 rows/block. W (64KB) + 8-row h tile staged in LDS.
__global__ __launch_bounds__(256) void k_gemm(const float* __restrict__ h, int hstride,
                                              const float* __restrict__ W,
                                              const float* __restrict__ inv_out,
                                              float* __restrict__ tmp) {
    __shared__ float Wl[FD * FD];   // 64 KB
    __shared__ float hs[8][FD];     // 4 KB
    const int tid = threadIdx.x;
    for (int i = tid; i < FD * FD / 4; i += 256)
        ((float4*)Wl)[i] = ((const float4*)W)[i];
    __syncthreads();

    const int row0 = blockIdx.x * 128;
    const int lane = tid & 31;   // float4 column group
    const int rl = tid >> 5;     // local row 0..7
    const float4* Wl4 = (const float4*)Wl;

    for (int it = 0; it < 16; ++it) {
        const int rbase = row0 + it * 8;
        {   // stage 8 rows of h
            int r = rbase + rl;
            float4 v = make_float4(0.f, 0.f, 0.f, 0.f);
            if (r < NN) v = ((const float4*)(h + (size_t)r * hstride))[lane];
            ((float4*)hs[rl])[lane] = v;
        }
        __syncthreads();
        const int r = rbase + rl;
        float4 acc = make_float4(0.f, 0.f, 0.f, 0.f);
        const float4* hrow4 = (const float4*)hs[rl];
        #pragma unroll
        for (int k4 = 0; k4 < FD / 4; ++k4) {
            float4 a = hrow4[k4];
            float4 w0 = Wl4[(k4 * 4 + 0) * 32 + lane];
            float4 w1 = Wl4[(k4 * 4 + 1) * 32 + lane];
            float4 w2 = Wl4[(k4 * 4 + 2) * 32 + lane];
            float4 w3 = Wl4[(k4 * 4 + 3) * 32 + lane];
            acc.x += a.x * w0.x; acc.y += a.x * w0.y; acc.z += a.x * w0.z; acc.w += a.x * w0.w;
            acc.x += a.y * w1.x; acc.y += a.y * w1.y; acc.z += a.y * w1.z; acc.w += a.y * w1.w;
            acc.x += a.z * w2.x; acc.y += a.z * w2.y; acc.z += a.z * w2.z; acc.w += a.z * w2.w;
            acc.x += a.w * w3.x; acc.y += a.w * w3.y; acc.z += a.w * w3.z; acc.w += a.w * w3.w;
        }
        if (r < NN) {
            float s = inv_out[r];
            acc.x *= s; acc.y *= s; acc.z *= s; acc.w *= s;
            ((float4*)(tmp + (size_t)r * FD))[lane] = acc;
        }
        __syncthreads();
    }
}

// ---------------- edge scatter: out[dst][off:off+128] += tmp[src][:] ----------------
__global__ void k_scatter(const float* __restrict__ tmp, const int* __restrict__ src,
                          const int* __restrict__ dst, float* __restrict__ out, int off) {
    const size_t total = (size_t)NE * 32;
    for (size_t i = (size_t)blockIdx.x * blockDim.x + threadIdx.x; i < total;
         i += (size_t)gridDim.x * blockDim.x) {
        int e = (int)(i >> 5);
        int c4 = (int)(i & 31);
        int s = src[e], d = dst[e];
        float4 v = ((const float4*)tmp)[(size_t)s * 32 + c4];
        float* base = out + (size_t)d * OS + off + c4 * 4;
        unsafeAtomicAdd(base + 0, v.x);
        unsafeAtomicAdd(base + 1, v.y);
        unsafeAtomicAdd(base + 2, v.z);
        unsafeAtomicAdd(base + 3, v.w);
    }
}

// ---------------- finalize: x = relu(x * inv_in[n] + b[c]) in place ----------------
__global__ void k_finalize(float* __restrict__ out, int off,
                           const float* __restrict__ inv_in, const float* __restrict__ b) {
    const size_t total = (size_t)NN * (FD / 4);
    for (size_t i = (size_t)blockIdx.x * blockDim.x + threadIdx.x; i < total;
         i += (size_t)gridDim.x * blockDim.x) {
        int n = (int)(i >> 5);
        int c4 = (int)(i & 31);
        float s = inv_in[n];
        float4* p = (float4*)(out + (size_t)n * OS + off) + c4;
        float4 v = *p;
        const float4 bb = ((const float4*)b)[c4];
        v.x = fmaxf(v.x * s + bb.x, 0.f);
        v.y = fmaxf(v.y * s + bb.y, 0.f);
        v.z = fmaxf(v.z * s + bb.z, 0.f);
        v.w = fmaxf(v.w * s + bb.w, 0.f);
        *p = v;
    }
}

extern "C" void kernel_launch(void* const* d_in, const int* in_sizes, int n_in,
                              void* d_out, int out_size, void* d_ws, size_t ws_size,
                              hipStream_t stream) {
    const float* feat = (const float*)d_in[0];
    const float* W0 = (const float*)d_in[1];
    const float* b0 = (const float*)d_in[2];
    const float* W1 = (const float*)d_in[3];
    const float* b1 = (const float*)d_in[4];
    const float* W2 = (const float*)d_in[5];
    const float* b2 = (const float*)d_in[6];
    const int* src = (const int*)d_in[7];
    const int* dst = (const int*)d_in[8];
    float* out = (float*)d_out;
    float* ws = (float*)d_ws;

    float* deg = ws;              // 2N floats (deg_out | deg_in)
    float* inv = ws + 2 * NN;     // 2N floats (inv_out | inv_in)
    float* tmp = ws + 4 * NN;     // N*FD floats

    hipMemsetAsync(deg, 0, 2 * NN * sizeof(float), stream);
    k_init_out<<<8192, 256, 0, stream>>>(feat, out);
    k_degrees<<<4096, 256, 0, stream>>>(src, dst, deg, deg + NN);
    k_invsqrt<<<(2 * NN + 255) / 256, 256, 0, stream>>>(deg, inv, 2 * NN);

    const float* Ws[3] = {W0, W1, W2};
    const float* bs[3] = {b0, b1, b2};
    const float* h = feat;
    int hstride = FD;
    for (int l = 0; l < 3; ++l) {
        k_gemm<<<(NN + 127) / 128, 256, 0, stream>>>(h, hstride, Ws[l], inv, tmp);
        k_scatter<<<16384, 256, 0, stream>>>(tmp, src, dst, out, FD * (l + 1));
        k_finalize<<<4096, 256, 0, stream>>>(out, FD * (l + 1), inv + NN, bs[l]);
        h = out + FD * (l + 1);
        hstride = OS;
    }
}

// Round 2
// 1271.825 us; speedup vs baseline: 6.9168x; 6.9168x over previous
//
#include <hip/hip_runtime.h>

#define NN 100000
#define NE 1600000
#define FD 128
#define OS 512   // output row stride: [feat | h1 | h2 | h3]

// ---------------- init: copy feat into cols 0:128 of out ----------------
// (cols 128:512 are fully overwritten by the per-layer gathers)
__global__ void k_init_out(const float* __restrict__ feat, float* __restrict__ out) {
    const size_t total = (size_t)NN * 32;  // float4s per feat row
    for (size_t i = (size_t)blockIdx.x * blockDim.x + threadIdx.x; i < total;
         i += (size_t)gridDim.x * blockDim.x) {
        size_t n = i >> 5;
        int c4 = (int)(i & 31);
        ((float4*)(out + n * OS))[c4] = ((const float4*)feat)[n * 32 + c4];
    }
}

// ---------------- degree histogram ----------------
__global__ void k_degrees(const int* __restrict__ src, const int* __restrict__ dst,
                          float* __restrict__ deg_out, float* __restrict__ deg_in) {
    for (int e = blockIdx.x * blockDim.x + threadIdx.x; e < NE;
         e += gridDim.x * blockDim.x) {
        unsafeAtomicAdd(&deg_out[src[e]], 1.0f);
        unsafeAtomicAdd(&deg_in[dst[e]], 1.0f);
    }
}

__global__ void k_invsqrt(const float* __restrict__ deg, float* __restrict__ inv, int n) {
    int i = blockIdx.x * blockDim.x + threadIdx.x;
    if (i < n) inv[i] = rsqrtf(fmaxf(deg[i], 1.0f));
}

// ---------------- single-block scan: row_ptr = exclusive_scan(in_deg) ----------------
__global__ __launch_bounds__(1024) void k_scan(const float* __restrict__ deg_in,
                                               int* __restrict__ row_ptr,
                                               int* __restrict__ cursor) {
    __shared__ int wsum[16];
    __shared__ int wscan[16];
    __shared__ int carry_s;
    const int tid = threadIdx.x;
    const int lane = tid & 63;
    const int wid = tid >> 6;
    if (tid == 0) carry_s = 0;
    __syncthreads();
    for (int base = 0; base < NN; base += 1024) {
        int i = base + tid;
        int v = (i < NN) ? (int)deg_in[i] : 0;
        int incl = v;
        #pragma unroll
        for (int off = 1; off < 64; off <<= 1) {
            int t = __shfl_up(incl, off, 64);
            if (lane >= off) incl += t;
        }
        if (lane == 63) wsum[wid] = incl;
        __syncthreads();
        if (wid == 0) {
            int s = (lane < 16) ? wsum[lane] : 0;
            #pragma unroll
            for (int off = 1; off < 16; off <<= 1) {
                int t = __shfl_up(s, off, 64);
                if (lane >= off) s += t;
            }
            if (lane < 16) wscan[lane] = s;
        }
        __syncthreads();
        int wbase = (wid > 0) ? wscan[wid - 1] : 0;
        int excl = carry_s + wbase + incl - v;
        if (i < NN) { row_ptr[i] = excl; cursor[i] = excl; }
        __syncthreads();
        if (tid == 0) carry_s += wscan[15];
        __syncthreads();
    }
    if (tid == 0) row_ptr[NN] = carry_s;
}

// ---------------- CSR fill: counting sort edges by dst ----------------
__global__ void k_csr_fill(const int* __restrict__ src, const int* __restrict__ dst,
                           int* __restrict__ cursor, int* __restrict__ col) {
    for (int e = blockIdx.x * blockDim.x + threadIdx.x; e < NE;
         e += gridDim.x * blockDim.x) {
        int pos = atomicAdd(&cursor[dst[e]], 1);
        col[pos] = src[e];
    }
}

// ---------------- GEMM: tmp[r][:] = inv_out[r] * (h[r][:] @ W) ----------------
__global__ __launch_bounds__(256) void k_gemm(const float* __restrict__ h, int hstride,
                                              const float* __restrict__ W,
                                              const float* __restrict__ inv_out,
                                              float* __restrict__ tmp) {
    __shared__ float Wl[FD * FD];   // 64 KB
    __shared__ float hs[8][FD];     // 4 KB
    const int tid = threadIdx.x;
    for (int i = tid; i < FD * FD / 4; i += 256)
        ((float4*)Wl)[i] = ((const float4*)W)[i];
    __syncthreads();

    const int row0 = blockIdx.x * 128;
    const int lane = tid & 31;   // float4 column group
    const int rl = tid >> 5;     // local row 0..7
    const float4* Wl4 = (const float4*)Wl;

    for (int it = 0; it < 16; ++it) {
        const int rbase = row0 + it * 8;
        {
            int r = rbase + rl;
            float4 v = make_float4(0.f, 0.f, 0.f, 0.f);
            if (r < NN) v = ((const float4*)(h + (size_t)r * hstride))[lane];
            ((float4*)hs[rl])[lane] = v;
        }
        __syncthreads();
        const int r = rbase + rl;
        float4 acc = make_float4(0.f, 0.f, 0.f, 0.f);
        const float4* hrow4 = (const float4*)hs[rl];
        #pragma unroll
        for (int k4 = 0; k4 < FD / 4; ++k4) {
            float4 a = hrow4[k4];
            float4 w0 = Wl4[(k4 * 4 + 0) * 32 + lane];
            float4 w1 = Wl4[(k4 * 4 + 1) * 32 + lane];
            float4 w2 = Wl4[(k4 * 4 + 2) * 32 + lane];
            float4 w3 = Wl4[(k4 * 4 + 3) * 32 + lane];
            acc.x += a.x * w0.x; acc.y += a.x * w0.y; acc.z += a.x * w0.z; acc.w += a.x * w0.w;
            acc.x += a.y * w1.x; acc.y += a.y * w1.y; acc.z += a.y * w1.z; acc.w += a.y * w1.w;
            acc.x += a.z * w2.x; acc.y += a.z * w2.y; acc.z += a.z * w2.z; acc.w += a.z * w2.w;
            acc.x += a.w * w3.x; acc.y += a.w * w3.y; acc.z += a.w * w3.z; acc.w += a.w * w3.w;
        }
        if (r < NN) {
            float s = inv_out[r];
            acc.x *= s; acc.y *= s; acc.z *= s; acc.w *= s;
            ((float4*)(tmp + (size_t)r * FD))[lane] = acc;
        }
        __syncthreads();
    }
}

// ---------------- gather: out[d][off:off+128] = relu(inv_in[d]*sum_{s in N(d)} tmp[s] + b) --
// one 64-lane wave per node, 4 waves per block; lane holds 2 channels (float2)
__global__ __launch_bounds__(256) void k_gather(const float* __restrict__ tmp,
                                                const int* __restrict__ row_ptr,
                                                const int* __restrict__ col,
                                                const float* __restrict__ inv_in,
                                                const float* __restrict__ b,
                                                float* __restrict__ out, int off) {
    const int wid = threadIdx.x >> 6;
    const int lane = threadIdx.x & 63;
    const int node = blockIdx.x * 4 + wid;
    if (node >= NN) return;
    const int beg = row_ptr[node], end = row_ptr[node + 1];
    const float2* t2 = (const float2*)tmp;
    float2 acc = make_float2(0.f, 0.f);
    int j = beg;
    for (; j + 1 < end; j += 2) {  // 2-way unroll for MLP
        int s0 = col[j], s1 = col[j + 1];
        float2 v0 = t2[(size_t)s0 * 64 + lane];
        float2 v1 = t2[(size_t)s1 * 64 + lane];
        acc.x += v0.x + v1.x;
        acc.y += v0.y + v1.y;
    }
    if (j < end) {
        int s0 = col[j];
        float2 v0 = t2[(size_t)s0 * 64 + lane];
        acc.x += v0.x;
        acc.y += v0.y;
    }
    const float s = inv_in[node];
    const float2 bb = ((const float2*)b)[lane];
    float2 r;
    r.x = fmaxf(acc.x * s + bb.x, 0.f);
    r.y = fmaxf(acc.y * s + bb.y, 0.f);
    ((float2*)(out + (size_t)node * OS + off))[lane] = r;
}

extern "C" void kernel_launch(void* const* d_in, const int* in_sizes, int n_in,
                              void* d_out, int out_size, void* d_ws, size_t ws_size,
                              hipStream_t stream) {
    const float* feat = (const float*)d_in[0];
    const float* W0 = (const float*)d_in[1];
    const float* b0 = (const float*)d_in[2];
    const float* W1 = (const float*)d_in[3];
    const float* b1 = (const float*)d_in[4];
    const float* W2 = (const float*)d_in[5];
    const float* b2 = (const float*)d_in[6];
    const int* src = (const int*)d_in[7];
    const int* dst = (const int*)d_in[8];
    float* out = (float*)d_out;
    float* ws = (float*)d_ws;

    float* tmp = ws;                          // N*FD floats (16B aligned at ws base)
    float* deg = ws + (size_t)NN * FD;        // 2N floats (deg_out | deg_in)
    float* inv = deg + 2 * NN;                // 2N floats (inv_out | inv_in)
    int* row_ptr = (int*)(inv + 2 * NN);      // N+1 ints
    int* cursor = row_ptr + NN + 1;           // N ints
    int* col = cursor + NN;                   // NE ints

    hipMemsetAsync(deg, 0, 2 * NN * sizeof(float), stream);
    k_init_out<<<4096, 256, 0, stream>>>(feat, out);
    k_degrees<<<4096, 256, 0, stream>>>(src, dst, deg, deg + NN);
    k_invsqrt<<<(2 * NN + 255) / 256, 256, 0, stream>>>(deg, inv, 2 * NN);
    k_scan<<<1, 1024, 0, stream>>>(deg + NN, row_ptr, cursor);
    k_csr_fill<<<4096, 256, 0, stream>>>(src, dst, cursor, col);

    const float* Ws[3] = {W0, W1, W2};
    const float* bs[3] = {b0, b1, b2};
    const float* h = feat;
    int hstride = FD;
    for (int l = 0; l < 3; ++l) {
        k_gemm<<<(NN + 127) / 128, 256, 0, stream>>>(h, hstride, Ws[l], inv, tmp);
        k_gather<<<(NN + 3) / 4, 256, 0, stream>>>(tmp, row_ptr, col, inv + NN, bs[l], out,
                                                   FD * (l + 1));
        h = out + FD * (l + 1);
        hstride = OS;
    }
}

// Round 3
// 1220.194 us; speedup vs baseline: 7.2095x; 1.0423x over previous
//
#include <hip/hip_runtime.h>

#define NN 100000
#define NE 1600000
#define FD 128
#define OS 512   // output row stride: [feat | h1 | h2 | h3]

// ---------------- init: copy feat into cols 0:128 of out ----------------
__global__ void k_init_out(const float* __restrict__ feat, float* __restrict__ out) {
    const size_t total = (size_t)NN * 32;  // float4s per feat row
    for (size_t i = (size_t)blockIdx.x * blockDim.x + threadIdx.x; i < total;
         i += (size_t)gridDim.x * blockDim.x) {
        size_t n = i >> 5;
        int c4 = (int)(i & 31);
        ((float4*)(out + n * OS))[c4] = ((const float4*)feat)[n * 32 + c4];
    }
}

// ---------------- degree histogram (int atomics, int4 edge loads) ----------------
__global__ void k_degrees(const int* __restrict__ src, const int* __restrict__ dst,
                          int* __restrict__ cnt_out, int* __restrict__ cnt_in) {
    const int total4 = NE / 4;
    for (int i = blockIdx.x * blockDim.x + threadIdx.x; i < total4;
         i += gridDim.x * blockDim.x) {
        int4 s = ((const int4*)src)[i];
        int4 d = ((const int4*)dst)[i];
        atomicAdd(&cnt_out[s.x], 1); atomicAdd(&cnt_out[s.y], 1);
        atomicAdd(&cnt_out[s.z], 1); atomicAdd(&cnt_out[s.w], 1);
        atomicAdd(&cnt_in[d.x], 1); atomicAdd(&cnt_in[d.y], 1);
        atomicAdd(&cnt_in[d.z], 1); atomicAdd(&cnt_in[d.w], 1);
    }
}

__global__ void k_invsqrt(const int* __restrict__ cnt, float* __restrict__ inv, int n) {
    int i = blockIdx.x * blockDim.x + threadIdx.x;
    if (i < n) inv[i] = rsqrtf((float)max(cnt[i], 1));
}

// ---------------- single-block scan, 4 elems/thread: row_ptr = excl_scan(cnt_in) ----
__global__ __launch_bounds__(1024) void k_scan(const int* __restrict__ cnt_in,
                                               int* __restrict__ row_ptr,
                                               int* __restrict__ cursor) {
    __shared__ int wsum[16];
    __shared__ int wscan[16];
    __shared__ int carry_s;
    const int tid = threadIdx.x;
    const int lane = tid & 63;
    const int wid = tid >> 6;
    if (tid == 0) carry_s = 0;
    __syncthreads();
    for (int base = 0; base < NN; base += 4096) {
        const int i0 = base + tid * 4;
        int4 v = make_int4(0, 0, 0, 0);
        if (i0 + 3 < NN) {
            v = ((const int4*)(cnt_in + base))[tid];
        } else {
            if (i0 < NN) v.x = cnt_in[i0];
            if (i0 + 1 < NN) v.y = cnt_in[i0 + 1];
            if (i0 + 2 < NN) v.z = cnt_in[i0 + 2];
            if (i0 + 3 < NN) v.w = cnt_in[i0 + 3];
        }
        const int s = v.x + v.y + v.z + v.w;
        int incl = s;
        #pragma unroll
        for (int off = 1; off < 64; off <<= 1) {
            int t = __shfl_up(incl, off, 64);
            if (lane >= off) incl += t;
        }
        if (lane == 63) wsum[wid] = incl;
        __syncthreads();
        if (wid == 0) {
            int t = (lane < 16) ? wsum[lane] : 0;
            #pragma unroll
            for (int off = 1; off < 16; off <<= 1) {
                int u = __shfl_up(t, off, 64);
                if (lane >= off) t += u;
            }
            if (lane < 16) wscan[lane] = t;
        }
        __syncthreads();
        const int wbase = (wid > 0) ? wscan[wid - 1] : 0;
        int p = carry_s + wbase + incl - s;
        if (i0 < NN) { row_ptr[i0] = p; cursor[i0] = p; }
        if (i0 + 1 < NN) { row_ptr[i0 + 1] = p + v.x; cursor[i0 + 1] = p + v.x; }
        if (i0 + 2 < NN) { row_ptr[i0 + 2] = p + v.x + v.y; cursor[i0 + 2] = p + v.x + v.y; }
        if (i0 + 3 < NN) { row_ptr[i0 + 3] = p + v.x + v.y + v.z; cursor[i0 + 3] = p + v.x + v.y + v.z; }
        __syncthreads();
        if (tid == 0) carry_s += wscan[15];
        __syncthreads();
    }
    if (tid == 0) row_ptr[NN] = carry_s;
}

// ---------------- CSR fill: counting sort edges by dst ----------------
__global__ void k_csr_fill(const int* __restrict__ src, const int* __restrict__ dst,
                           int* __restrict__ cursor, int* __restrict__ col) {
    for (int e = blockIdx.x * blockDim.x + threadIdx.x; e < NE;
         e += gridDim.x * blockDim.x) {
        int pos = atomicAdd(&cursor[dst[e]], 1);
        col[pos] = src[e];
    }
}

// ---------------- GEMM: tmp[r][:] = inv_out[r] * (h[r][:] @ W) ----------------
// 4 rows x 4 cols per thread: per k4 iter 8 ds_read_b128 vs 64 FMA -> VALU-bound.
__global__ __launch_bounds__(256) void k_gemm(const float* __restrict__ h, int hstride,
                                              const float* __restrict__ W,
                                              const float* __restrict__ inv_out,
                                              float* __restrict__ tmp) {
    __shared__ float Wl[FD * FD];   // 64 KB
    __shared__ float hs[32][FD];    // 16 KB
    const int tid = threadIdx.x;
    for (int i = tid; i < FD * FD / 4; i += 256)
        ((float4*)Wl)[i] = ((const float4*)W)[i];

    const int row0 = blockIdx.x * 128;
    const int lane = tid & 31;   // float4 column group
    const int g = tid >> 5;      // 0..7 -> staged rows 4g..4g+3
    const float4* Wl4 = (const float4*)Wl;

    for (int it = 0; it < 4; ++it) {
        const int rbase = row0 + it * 32;
        __syncthreads();   // protect Wl (first iter) and hs (later iters)
        #pragma unroll
        for (int q = 0; q < 4; ++q) {
            int idx = q * 256 + tid;      // 0..1023
            int rr = idx >> 5, cc = idx & 31;
            int r = rbase + rr;
            float4 v = make_float4(0.f, 0.f, 0.f, 0.f);
            if (r < NN) v = ((const float4*)(h + (size_t)r * hstride))[cc];
            ((float4*)hs[rr])[cc] = v;
        }
        __syncthreads();
        float4 acc0 = make_float4(0.f, 0.f, 0.f, 0.f);
        float4 acc1 = acc0, acc2 = acc0, acc3 = acc0;
        const float4* h0 = (const float4*)hs[4 * g + 0];
        const float4* h1 = (const float4*)hs[4 * g + 1];
        const float4* h2 = (const float4*)hs[4 * g + 2];
        const float4* h3 = (const float4*)hs[4 * g + 3];
        #pragma unroll 8
        for (int k4 = 0; k4 < FD / 4; ++k4) {
            float4 a0 = h0[k4], a1 = h1[k4], a2 = h2[k4], a3 = h3[k4];
            float4 w0 = Wl4[(k4 * 4 + 0) * 32 + lane];
            float4 w1 = Wl4[(k4 * 4 + 1) * 32 + lane];
            float4 w2 = Wl4[(k4 * 4 + 2) * 32 + lane];
            float4 w3 = Wl4[(k4 * 4 + 3) * 32 + lane];
            acc0.x += a0.x * w0.x + a0.y * w1.x + a0.z * w2.x + a0.w * w3.x;
            acc0.y += a0.x * w0.y + a0.y * w1.y + a0.z * w2.y + a0.w * w3.y;
            acc0.z += a0.x * w0.z + a0.y * w1.z + a0.z * w2.z + a0.w * w3.z;
            acc0.w += a0.x * w0.w + a0.y * w1.w + a0.z * w2.w + a0.w * w3.w;
            acc1.x += a1.x * w0.x + a1.y * w1.x + a1.z * w2.x + a1.w * w3.x;
            acc1.y += a1.x * w0.y + a1.y * w1.y + a1.z * w2.y + a1.w * w3.y;
            acc1.z += a1.x * w0.z + a1.y * w1.z + a1.z * w2.z + a1.w * w3.z;
            acc1.w += a1.x * w0.w + a1.y * w1.w + a1.z * w2.w + a1.w * w3.w;
            acc2.x += a2.x * w0.x + a2.y * w1.x + a2.z * w2.x + a2.w * w3.x;
            acc2.y += a2.x * w0.y + a2.y * w1.y + a2.z * w2.y + a2.w * w3.y;
            acc2.z += a2.x * w0.z + a2.y * w1.z + a2.z * w2.z + a2.w * w3.z;
            acc2.w += a2.x * w0.w + a2.y * w1.w + a2.z * w2.w + a2.w * w3.w;
            acc3.x += a3.x * w0.x + a3.y * w1.x + a3.z * w2.x + a3.w * w3.x;
            acc3.y += a3.x * w0.y + a3.y * w1.y + a3.z * w2.y + a3.w * w3.y;
            acc3.z += a3.x * w0.z + a3.y * w1.z + a3.z * w2.z + a3.w * w3.z;
            acc3.w += a3.x * w0.w + a3.y * w1.w + a3.z * w2.w + a3.w * w3.w;
        }
        const int r0 = rbase + 4 * g;
        if (r0 + 3 < NN) {
            float s0 = inv_out[r0], s1 = inv_out[r0 + 1], s2 = inv_out[r0 + 2], s3 = inv_out[r0 + 3];
            acc0.x *= s0; acc0.y *= s0; acc0.z *= s0; acc0.w *= s0;
            acc1.x *= s1; acc1.y *= s1; acc1.z *= s1; acc1.w *= s1;
            acc2.x *= s2; acc2.y *= s2; acc2.z *= s2; acc2.w *= s2;
            acc3.x *= s3; acc3.y *= s3; acc3.z *= s3; acc3.w *= s3;
            ((float4*)(tmp + (size_t)(r0 + 0) * FD))[lane] = acc0;
            ((float4*)(tmp + (size_t)(r0 + 1) * FD))[lane] = acc1;
            ((float4*)(tmp + (size_t)(r0 + 2) * FD))[lane] = acc2;
            ((float4*)(tmp + (size_t)(r0 + 3) * FD))[lane] = acc3;
        } else {
            float4 accs[4] = {acc0, acc1, acc2, acc3};
            for (int rr = 0; rr < 4; ++rr) {
                int r = r0 + rr;
                if (r < NN) {
                    float s = inv_out[r];
                    float4 a = accs[rr];
                    a.x *= s; a.y *= s; a.z *= s; a.w *= s;
                    ((float4*)(tmp + (size_t)r * FD))[lane] = a;
                }
            }
        }
    }
}

// ---------------- gather: out[d][off:off+128] = relu(inv_in[d]*sum tmp[s] + b) ----
__global__ __launch_bounds__(256) void k_gather(const float* __restrict__ tmp,
                                                const int* __restrict__ row_ptr,
                                                const int* __restrict__ col,
                                                const float* __restrict__ inv_in,
                                                const float* __restrict__ b,
                                                float* __restrict__ out, int off) {
    const int wid = threadIdx.x >> 6;
    const int lane = threadIdx.x & 63;
    const int node = blockIdx.x * 4 + wid;
    if (node >= NN) return;
    const int beg = row_ptr[node], end = row_ptr[node + 1];
    const float2* t2 = (const float2*)tmp;
    float2 acc = make_float2(0.f, 0.f);
    int j = beg;
    for (; j + 3 < end; j += 4) {
        int s0 = col[j], s1 = col[j + 1], s2 = col[j + 2], s3 = col[j + 3];
        float2 v0 = t2[(size_t)s0 * 64 + lane];
        float2 v1 = t2[(size_t)s1 * 64 + lane];
        float2 v2 = t2[(size_t)s2 * 64 + lane];
        float2 v3 = t2[(size_t)s3 * 64 + lane];
        acc.x += (v0.x + v1.x) + (v2.x + v3.x);
        acc.y += (v0.y + v1.y) + (v2.y + v3.y);
    }
    for (; j < end; ++j) {
        int s0 = col[j];
        float2 v0 = t2[(size_t)s0 * 64 + lane];
        acc.x += v0.x;
        acc.y += v0.y;
    }
    const float s = inv_in[node];
    const float2 bb = ((const float2*)b)[lane];
    float2 r;
    r.x = fmaxf(acc.x * s + bb.x, 0.f);
    r.y = fmaxf(acc.y * s + bb.y, 0.f);
    ((float2*)(out + (size_t)node * OS + off))[lane] = r;
}

extern "C" void kernel_launch(void* const* d_in, const int* in_sizes, int n_in,
                              void* d_out, int out_size, void* d_ws, size_t ws_size,
                              hipStream_t stream) {
    const float* feat = (const float*)d_in[0];
    const float* W0 = (const float*)d_in[1];
    const float* b0 = (const float*)d_in[2];
    const float* W1 = (const float*)d_in[3];
    const float* b1 = (const float*)d_in[4];
    const float* W2 = (const float*)d_in[5];
    const float* b2 = (const float*)d_in[6];
    const int* src = (const int*)d_in[7];
    const int* dst = (const int*)d_in[8];
    float* out = (float*)d_out;
    float* ws = (float*)d_ws;

    float* tmp = ws;                          // N*FD floats
    int* cnt = (int*)(ws + (size_t)NN * FD);  // 2N ints (cnt_out | cnt_in)
    float* inv = (float*)(cnt + 2 * NN);      // 2N floats (inv_out | inv_in)
    int* row_ptr = (int*)(inv + 2 * NN);      // N+1 ints
    int* cursor = row_ptr + NN + 1;           // N ints
    int* col = cursor + NN;                   // NE ints

    hipMemsetAsync(cnt, 0, 2 * NN * sizeof(int), stream);
    k_init_out<<<4096, 256, 0, stream>>>(feat, out);
    k_degrees<<<2048, 256, 0, stream>>>(src, dst, cnt, cnt + NN);
    k_invsqrt<<<(2 * NN + 255) / 256, 256, 0, stream>>>(cnt, inv, 2 * NN);
    k_scan<<<1, 1024, 0, stream>>>(cnt + NN, row_ptr, cursor);
    k_csr_fill<<<4096, 256, 0, stream>>>(src, dst, cursor, col);

    const float* Ws[3] = {W0, W1, W2};
    const float* bs[3] = {b0, b1, b2};
    const float* h = feat;
    int hstride = FD;
    for (int l = 0; l < 3; ++l) {
        k_gemm<<<(NN + 127) / 128, 256, 0, stream>>>(h, hstride, Ws[l], inv, tmp);
        k_gather<<<(NN + 3) / 4, 256, 0, stream>>>(tmp, row_ptr, col, inv + NN, bs[l], out,
                                                   FD * (l + 1));
        h = out + FD * (l + 1);
        hstride = OS;
    }
}

// Round 4
// 932.928 us; speedup vs baseline: 9.4294x; 1.3079x over previous
//
#include <hip/hip_runtime.h>

#define NN 100000
#define NE 1600000
#define FD 128
#define OS 512   // output row stride: [feat | h1 | h2 | h3]
#define LDA 136  // LDS row stride in bf16 elems (128 + 8 pad -> bank-conflict-free)

typedef __attribute__((ext_vector_type(8))) short short8;
typedef __attribute__((ext_vector_type(4))) float f32x4;

__device__ __forceinline__ short f2bf(float x) {
    unsigned u = __float_as_uint(x);
    u = (u + 0x7fff + ((u >> 16) & 1)) >> 16;   // round-to-nearest-even
    return (short)u;
}

// ---------------- init: copy feat into cols 0:128 of out ----------------
__global__ void k_init_out(const float* __restrict__ feat, float* __restrict__ out) {
    const size_t total = (size_t)NN * 32;  // float4s per feat row
    for (size_t i = (size_t)blockIdx.x * blockDim.x + threadIdx.x; i < total;
         i += (size_t)gridDim.x * blockDim.x) {
        size_t n = i >> 5;
        int c4 = (int)(i & 31);
        ((float4*)(out + n * OS))[c4] = ((const float4*)feat)[n * 32 + c4];
    }
}

// ---------------- prep: Wt[l][n][k] = bf16(W_l[k][n]) ----------------
__global__ void k_prep_w(const float* __restrict__ W0, const float* __restrict__ W1,
                         const float* __restrict__ W2, short* __restrict__ Wt) {
    int i = blockIdx.x * blockDim.x + threadIdx.x;
    if (i >= 3 * FD * FD) return;
    int l = i >> 14, r = i & (FD * FD - 1);
    int n = r >> 7, k = r & 127;
    const float* W = (l == 0) ? W0 : ((l == 1) ? W1 : W2);
    Wt[i] = f2bf(W[k * FD + n]);   // i = l*16384 + n*128 + k
}

// ---------------- degree histogram (int atomics, int4 edge loads) ----------------
__global__ void k_degrees(const int* __restrict__ src, const int* __restrict__ dst,
                          int* __restrict__ cnt_out, int* __restrict__ cnt_in) {
    const int total4 = NE / 4;
    for (int i = blockIdx.x * blockDim.x + threadIdx.x; i < total4;
         i += gridDim.x * blockDim.x) {
        int4 s = ((const int4*)src)[i];
        int4 d = ((const int4*)dst)[i];
        atomicAdd(&cnt_out[s.x], 1); atomicAdd(&cnt_out[s.y], 1);
        atomicAdd(&cnt_out[s.z], 1); atomicAdd(&cnt_out[s.w], 1);
        atomicAdd(&cnt_in[d.x], 1); atomicAdd(&cnt_in[d.y], 1);
        atomicAdd(&cnt_in[d.z], 1); atomicAdd(&cnt_in[d.w], 1);
    }
}

__global__ void k_invsqrt(const int* __restrict__ cnt, float* __restrict__ inv, int n) {
    int i = blockIdx.x * blockDim.x + threadIdx.x;
    if (i < n) inv[i] = rsqrtf((float)max(cnt[i], 1));
}

// ---------------- single-block scan, 4 elems/thread ----------------
__global__ __launch_bounds__(1024) void k_scan(const int* __restrict__ cnt_in,
                                               int* __restrict__ row_ptr,
                                               int* __restrict__ cursor) {
    __shared__ int wsum[16];
    __shared__ int wscan[16];
    __shared__ int carry_s;
    const int tid = threadIdx.x;
    const int lane = tid & 63;
    const int wid = tid >> 6;
    if (tid == 0) carry_s = 0;
    __syncthreads();
    for (int base = 0; base < NN; base += 4096) {
        const int i0 = base + tid * 4;
        int4 v = make_int4(0, 0, 0, 0);
        if (i0 + 3 < NN) {
            v = ((const int4*)(cnt_in + base))[tid];
        } else {
            if (i0 < NN) v.x = cnt_in[i0];
            if (i0 + 1 < NN) v.y = cnt_in[i0 + 1];
            if (i0 + 2 < NN) v.z = cnt_in[i0 + 2];
            if (i0 + 3 < NN) v.w = cnt_in[i0 + 3];
        }
        const int s = v.x + v.y + v.z + v.w;
        int incl = s;
        #pragma unroll
        for (int off = 1; off < 64; off <<= 1) {
            int t = __shfl_up(incl, off, 64);
            if (lane >= off) incl += t;
        }
        if (lane == 63) wsum[wid] = incl;
        __syncthreads();
        if (wid == 0) {
            int t = (lane < 16) ? wsum[lane] : 0;
            #pragma unroll
            for (int off = 1; off < 16; off <<= 1) {
                int u = __shfl_up(t, off, 64);
                if (lane >= off) t += u;
            }
            if (lane < 16) wscan[lane] = t;
        }
        __syncthreads();
        const int wbase = (wid > 0) ? wscan[wid - 1] : 0;
        int p = carry_s + wbase + incl - s;
        if (i0 < NN) { row_ptr[i0] = p; cursor[i0] = p; }
        if (i0 + 1 < NN) { row_ptr[i0 + 1] = p + v.x; cursor[i0 + 1] = p + v.x; }
        if (i0 + 2 < NN) { row_ptr[i0 + 2] = p + v.x + v.y; cursor[i0 + 2] = p + v.x + v.y; }
        if (i0 + 3 < NN) { row_ptr[i0 + 3] = p + v.x + v.y + v.z; cursor[i0 + 3] = p + v.x + v.y + v.z; }
        __syncthreads();
        if (tid == 0) carry_s += wscan[15];
        __syncthreads();
    }
    if (tid == 0) row_ptr[NN] = carry_s;
}

// ---------------- CSR fill: counting sort edges by dst ----------------
__global__ void k_csr_fill(const int* __restrict__ src, const int* __restrict__ dst,
                           int* __restrict__ cursor, int* __restrict__ col) {
    for (int e = blockIdx.x * blockDim.x + threadIdx.x; e < NE;
         e += gridDim.x * blockDim.x) {
        int pos = atomicAdd(&cursor[dst[e]], 1);
        col[pos] = src[e];
    }
}

// ---------------- MFMA GEMM: tmp[r][:] = inv_out[r] * (bf16(h[r][:]) @ bf16(W)) ----
// block = 256 thr (4 waves); 128-row tile, 2 sub-iters of 64 rows; wave owns 16 rows.
__global__ __launch_bounds__(256) void k_gemm(const float* __restrict__ h, int hstride,
                                              const short* __restrict__ Wt,
                                              const float* __restrict__ inv_out,
                                              float* __restrict__ tmp) {
    __shared__ short Ws[FD * LDA];   // Wt[n][k], padded rows: 34 KB
    __shared__ short hA[64 * LDA];   // h tile bf16, padded rows: 17 KB
    const int tid = threadIdx.x;
    // stage Wt (coalesced 16B chunks), bank-friendly padded rows
    for (int i = tid; i < FD * 16; i += 256) {   // 2048 chunks of 8 bf16
        int n = i >> 4, c = i & 15;
        short8 v = *(const short8*)(Wt + n * FD + c * 8);
        *(short8*)(&Ws[n * LDA + c * 8]) = v;
    }
    const int row0 = blockIdx.x * 128;
    const int wid = tid >> 6, lane = tid & 63;
    const int m = lane & 15, quad = lane >> 4;

    for (int sub = 0; sub < 2; ++sub) {
        const int rbase = row0 + sub * 64;
        __syncthreads();   // sub0: Ws staged; sub>0: prev compute done before hA overwrite
        // stage 64 rows of h -> bf16 in hA
        for (int i = tid; i < 64 * 32; i += 256) {   // float4 chunks
            int r = i >> 5, c4 = i & 31;
            int gr = rbase + r;
            float4 v = make_float4(0.f, 0.f, 0.f, 0.f);
            if (gr < NN) v = ((const float4*)(h + (size_t)gr * hstride))[c4];
            short4 b;
            b.x = f2bf(v.x); b.y = f2bf(v.y); b.z = f2bf(v.z); b.w = f2bf(v.w);
            *(short4*)(&hA[r * LDA + c4 * 4]) = b;
        }
        __syncthreads();
        const int rtile = rbase + wid * 16;          // this wave's 16 rows
        // A fragments: reused across all 8 col-tiles
        short8 a0 = *(const short8*)(&hA[(wid * 16 + m) * LDA + 0 * 32 + quad * 8]);
        short8 a1 = *(const short8*)(&hA[(wid * 16 + m) * LDA + 1 * 32 + quad * 8]);
        short8 a2 = *(const short8*)(&hA[(wid * 16 + m) * LDA + 2 * 32 + quad * 8]);
        short8 a3 = *(const short8*)(&hA[(wid * 16 + m) * LDA + 3 * 32 + quad * 8]);
        // row scales for this lane's 4 output rows
        float s0, s1, s2, s3;
        {
            int r = rtile + quad * 4;
            s0 = (r + 0 < NN) ? inv_out[r + 0] : 0.f;
            s1 = (r + 1 < NN) ? inv_out[r + 1] : 0.f;
            s2 = (r + 2 < NN) ? inv_out[r + 2] : 0.f;
            s3 = (r + 3 < NN) ? inv_out[r + 3] : 0.f;
        }
        #pragma unroll
        for (int ct = 0; ct < 8; ++ct) {
            f32x4 acc = {0.f, 0.f, 0.f, 0.f};
            short8 b0 = *(const short8*)(&Ws[(ct * 16 + m) * LDA + 0 * 32 + quad * 8]);
            short8 b1 = *(const short8*)(&Ws[(ct * 16 + m) * LDA + 1 * 32 + quad * 8]);
            short8 b2 = *(const short8*)(&Ws[(ct * 16 + m) * LDA + 2 * 32 + quad * 8]);
            short8 b3 = *(const short8*)(&Ws[(ct * 16 + m) * LDA + 3 * 32 + quad * 8]);
            acc = __builtin_amdgcn_mfma_f32_16x16x32_bf16(a0, b0, acc, 0, 0, 0);
            acc = __builtin_amdgcn_mfma_f32_16x16x32_bf16(a1, b1, acc, 0, 0, 0);
            acc = __builtin_amdgcn_mfma_f32_16x16x32_bf16(a2, b2, acc, 0, 0, 0);
            acc = __builtin_amdgcn_mfma_f32_16x16x32_bf16(a3, b3, acc, 0, 0, 0);
            // D: col = ct*16 + m, rows = rtile + quad*4 + reg
            const int r = rtile + quad * 4;
            const int c = ct * 16 + m;
            if (r + 3 < NN) {
                tmp[(size_t)(r + 0) * FD + c] = acc[0] * s0;
                tmp[(size_t)(r + 1) * FD + c] = acc[1] * s1;
                tmp[(size_t)(r + 2) * FD + c] = acc[2] * s2;
                tmp[(size_t)(r + 3) * FD + c] = acc[3] * s3;
            } else {
                if (r + 0 < NN) tmp[(size_t)(r + 0) * FD + c] = acc[0] * s0;
                if (r + 1 < NN) tmp[(size_t)(r + 1) * FD + c] = acc[1] * s1;
                if (r + 2 < NN) tmp[(size_t)(r + 2) * FD + c] = acc[2] * s2;
                if (r + 3 < NN) tmp[(size_t)(r + 3) * FD + c] = acc[3] * s3;
            }
        }
    }
}

// ---------------- gather: out[d][off:off+128] = relu(inv_in[d]*sum tmp[s] + b) ----
__global__ __launch_bounds__(256) void k_gather(const float* __restrict__ tmp,
                                                const int* __restrict__ row_ptr,
                                                const int* __restrict__ col,
                                                const float* __restrict__ inv_in,
                                                const float* __restrict__ b,
                                                float* __restrict__ out, int off) {
    const int wid = threadIdx.x >> 6;
    const int lane = threadIdx.x & 63;
    const int node = blockIdx.x * 4 + wid;
    if (node >= NN) return;
    const int beg = row_ptr[node], end = row_ptr[node + 1];
    const float2* t2 = (const float2*)tmp;
    float2 acc = make_float2(0.f, 0.f);
    int j = beg;
    for (; j + 3 < end; j += 4) {
        int s0 = col[j], s1 = col[j + 1], s2 = col[j + 2], s3 = col[j + 3];
        float2 v0 = t2[(size_t)s0 * 64 + lane];
        float2 v1 = t2[(size_t)s1 * 64 + lane];
        float2 v2 = t2[(size_t)s2 * 64 + lane];
        float2 v3 = t2[(size_t)s3 * 64 + lane];
        acc.x += (v0.x + v1.x) + (v2.x + v3.x);
        acc.y += (v0.y + v1.y) + (v2.y + v3.y);
    }
    for (; j < end; ++j) {
        int s0 = col[j];
        float2 v0 = t2[(size_t)s0 * 64 + lane];
        acc.x += v0.x;
        acc.y += v0.y;
    }
    const float s = inv_in[node];
    const float2 bb = ((const float2*)b)[lane];
    float2 r;
    r.x = fmaxf(acc.x * s + bb.x, 0.f);
    r.y = fmaxf(acc.y * s + bb.y, 0.f);
    ((float2*)(out + (size_t)node * OS + off))[lane] = r;
}

extern "C" void kernel_launch(void* const* d_in, const int* in_sizes, int n_in,
                              void* d_out, int out_size, void* d_ws, size_t ws_size,
                              hipStream_t stream) {
    const float* feat = (const float*)d_in[0];
    const float* W0 = (const float*)d_in[1];
    const float* b0 = (const float*)d_in[2];
    const float* W1 = (const float*)d_in[3];
    const float* b1 = (const float*)d_in[4];
    const float* W2 = (const float*)d_in[5];
    const float* b2 = (const float*)d_in[6];
    const int* src = (const int*)d_in[7];
    const int* dst = (const int*)d_in[8];
    float* out = (float*)d_out;
    float* ws = (float*)d_ws;

    float* tmp = ws;                          // N*FD floats
    int* cnt = (int*)(ws + (size_t)NN * FD);  // 2N ints (cnt_out | cnt_in)
    float* inv = (float*)(cnt + 2 * NN);      // 2N floats (inv_out | inv_in)
    int* row_ptr = (int*)(inv + 2 * NN);      // N+1 ints
    int* cursor = row_ptr + NN + 1;           // N ints
    int* col = cursor + NN;                   // NE ints
    short* Wt = (short*)(col + NE);           // 3*FD*FD bf16

    hipMemsetAsync(cnt, 0, 2 * NN * sizeof(int), stream);
    k_init_out<<<4096, 256, 0, stream>>>(feat, out);
    k_prep_w<<<(3 * FD * FD + 255) / 256, 256, 0, stream>>>(W0, W1, W2, Wt);
    k_degrees<<<2048, 256, 0, stream>>>(src, dst, cnt, cnt + NN);
    k_invsqrt<<<(2 * NN + 255) / 256, 256, 0, stream>>>(cnt, inv, 2 * NN);
    k_scan<<<1, 1024, 0, stream>>>(cnt + NN, row_ptr, cursor);
    k_csr_fill<<<4096, 256, 0, stream>>>(src, dst, cursor, col);

    const float* bs[3] = {b0, b1, b2};
    const float* h = feat;
    int hstride = FD;
    for (int l = 0; l < 3; ++l) {
        k_gemm<<<(NN + 127) / 128, 256, 0, stream>>>(h, hstride, Wt + l * FD * FD, inv, tmp);
        k_gather<<<(NN + 3) / 4, 256, 0, stream>>>(tmp, row_ptr, col, inv + NN, bs[l], out,
                                                   FD * (l + 1));
        h = out + FD * (l + 1);
        hstride = OS;
    }
}